// Round 4
// baseline (2932.143 us; speedup 1.0000x reference)
//
#include <hip/hip_runtime.h>
#include <cstdint>
#include <cstddef>

#define NODE 64
#define EDGEF 32
#define UPF 160   // 2*NODE + EDGEF
#define RD 256
#define UT_STRIDE 162  // 160 padded: float2 reads -> 2-way bank aliasing (free)

__device__ __forceinline__ float eluf(float x) { return x > 0.f ? x : expm1f(x); }

// ---------------------------------------------------------------------------
// CSR build
__global__ void k_count(const int* __restrict__ dst, int* cnt, int E) {
    int e = blockIdx.x * 256 + threadIdx.x;
    if (e < E) atomicAdd(&cnt[dst[e]], 1);
}

__global__ void k_scanA(const int* __restrict__ cnt, int* starts, int* bsum, int N) {
    __shared__ int sh[256];
    int t = threadIdx.x;
    int base = blockIdx.x * 1024 + t * 4;
    int v0 = 0, v1 = 0, v2 = 0, v3 = 0;
    if (base + 0 < N) v0 = cnt[base + 0];
    if (base + 1 < N) v1 = cnt[base + 1];
    if (base + 2 < N) v2 = cnt[base + 2];
    if (base + 3 < N) v3 = cnt[base + 3];
    int tot = v0 + v1 + v2 + v3;
    sh[t] = tot;
    __syncthreads();
    for (int off = 1; off < 256; off <<= 1) {
        int add = (t >= off) ? sh[t - off] : 0;
        __syncthreads();
        sh[t] += add;
        __syncthreads();
    }
    int excl = sh[t] - tot;
    if (base + 0 < N) starts[base + 0] = excl;
    if (base + 1 < N) starts[base + 1] = excl + v0;
    if (base + 2 < N) starts[base + 2] = excl + v0 + v1;
    if (base + 3 < N) starts[base + 3] = excl + v0 + v1 + v2;
    if (t == 255) bsum[blockIdx.x] = sh[255];
}

__global__ void k_scanB(const int* __restrict__ bsum, int* boff, int nb, int* starts, int N) {
    if (threadIdx.x == 0 && blockIdx.x == 0) {
        int run = 0;
        for (int b = 0; b < nb; ++b) { boff[b] = run; run += bsum[b]; }
        starts[N] = run;
    }
}

__global__ void k_scanC(const int* __restrict__ boff, int* starts, int* cursor, int N) {
    int i = blockIdx.x * 256 + threadIdx.x;
    if (i < N) {
        int v = starts[i] + boff[i >> 10];
        starts[i] = v;
        cursor[i] = v;
    }
}

// ---------------------------------------------------------------------------
// Fused CSR-fill + edge FFN: per edge compute w_bond * relu(ea@E_W + E_b),
// write contiguous 128B row into medge[pos] (CSR slot). No float atomics.
__global__ void k_fill_mij(const float* __restrict__ ea, const int* __restrict__ src,
                           const int* __restrict__ dst, const float* __restrict__ wb,
                           const float* __restrict__ EW, const float* __restrict__ Eb,
                           int* cursor, int* esrc, float* ewS, float* medge, int E) {
    __shared__ float ew_s[EDGEF * EDGEF];
    __shared__ float eb_s[EDGEF];
    int tid = threadIdx.x;
    for (int i = tid; i < EDGEF * EDGEF; i += 256) ew_s[i] = EW[i];
    if (tid < EDGEF) eb_s[tid] = Eb[tid];
    __syncthreads();
    int e = blockIdx.x * 256 + tid;
    if (e >= E) return;
    float a[EDGEF];
    const float4* row = (const float4*)(ea + (size_t)e * EDGEF);
#pragma unroll
    for (int q = 0; q < 8; ++q) {
        float4 v = row[q];
        a[4*q] = v.x; a[4*q+1] = v.y; a[4*q+2] = v.z; a[4*q+3] = v.w;
    }
    float m[EDGEF];
#pragma unroll
    for (int j = 0; j < EDGEF; ++j) m[j] = eb_s[j];
#pragma unroll
    for (int k = 0; k < EDGEF; ++k) {
        float ak = a[k];
#pragma unroll
        for (int j = 0; j < EDGEF; ++j) m[j] = fmaf(ak, ew_s[k*EDGEF + j], m[j]);
    }
    float w = wb[e];
    int pos = atomicAdd(&cursor[dst[e]], 1);
    esrc[pos] = src[e];
    ewS[pos] = w;
    float4* mp = (float4*)(medge + (size_t)pos * EDGEF);
#pragma unroll
    for (int q = 0; q < 8; ++q) {
        float4 v = { w * fmaxf(m[4*q], 0.f),   w * fmaxf(m[4*q+1], 0.f),
                     w * fmaxf(m[4*q+2], 0.f), w * fmaxf(m[4*q+3], 0.f) };
        mp[q] = v;
    }
}

// ---------------------------------------------------------------------------
// aggrE[n] = elu( sum_{edges->n} medge[i] )  -- sequential coalesced reads.
__global__ __launch_bounds__(256) void k_aggrE(const float* __restrict__ medge,
                                               const int* __restrict__ starts,
                                               float* __restrict__ aggrE_elu, int N) {
    int tid = threadIdx.x;
    int lane = tid & 63, wid = tid >> 6;
    int half = lane >> 5, ch = lane & 31;
    int nwaves = gridDim.x * 4;
    for (int n = blockIdx.x * 4 + wid; n < N; n += nwaves) {
        int s0 = starts[n], s1 = starts[n + 1];
        float acc = 0.f;
        for (int i = s0 + half; i < s1; i += 2)
            acc += medge[(size_t)i * EDGEF + ch];
        acc += __shfl_xor(acc, 32, 64);
        if (lane < EDGEF) aggrE_elu[(size_t)n * EDGEF + lane] = eluf(acc);
    }
}

// ---------------------------------------------------------------------------
// Fused message-passing depth. Wave per node; lane j owns channel j.
// Gather path: lane-parallel vector load of h[src] row (256B coalesced,
// pipelined 1 edge ahead in a register) -> per-wave LDS slot -> 16 uniform
// ds_read_b128 broadcasts against V column held in VGPRs. Avoids the
// scalar-cache (s_load) path entirely.
__global__ __launch_bounds__(512, 6) void k_node(
    const float* __restrict__ h_in, float* __restrict__ h_out,
    const int* __restrict__ starts, const int* __restrict__ esrc,
    const float* __restrict__ ewS, const float* __restrict__ aggrE_elu,
    const float* __restrict__ VW, const float* __restrict__ Vb,
    const float* __restrict__ UW, const float* __restrict__ Ub,
    const float* __restrict__ watoms, int N) {
    __shared__ float lds_Ut[NODE * UT_STRIDE];   // 41.4 KB
    __shared__ float lds_up[8 * UPF];            // 5 KB
    __shared__ float lds_slot[8 * NODE];         // 2 KB: per-wave gather slot
    int tid = threadIdx.x;
    for (int idx = tid; idx < UPF * NODE; idx += 512) {
        int j = idx & 63, t2 = idx >> 6;
        lds_Ut[j * UT_STRIDE + t2] = UW[idx];
    }
    int lane = tid & 63, wid = tid >> 6;
    float vcol[NODE];
#pragma unroll
    for (int k = 0; k < NODE; ++k) vcol[k] = VW[k * NODE + lane];
    float vb = Vb[lane];
    float ub = Ub[lane];
    __syncthreads();
    float* myup = lds_up + wid * UPF;
    float* slot = lds_slot + wid * NODE;
    const float4* slot4 = (const float4*)slot;
    int nwaves = gridDim.x * 8;
    for (int n = blockIdx.x * 8 + wid; n < N; n += nwaves) {
        int s0 = starts[n], s1 = starts[n + 1];
        int deg = s1 - s0;
        float acc = 0.f;
        // register-carried prefetch of the gathered row (vector loads)
        float hvC = 0.f;
        if (deg > 0) {
            int sidx0 = esrc[s0];
            hvC = h_in[(size_t)sidx0 * NODE + lane];
        }
        for (int i = 0; i < deg; ++i) {
            // issue next row load (stays in flight during compute)
            float hvN = 0.f;
            if (i + 1 < deg) {
                int sidxN = esrc[s0 + i + 1];
                hvN = h_in[(size_t)sidxN * NODE + lane];
            }
            float we = ewS[s0 + i];
            slot[lane] = hvC;                       // waits only on hvC
            // dot from uniform b128 broadcasts (conflict-free)
            float d0 = 0.f, d1 = 0.f, d2 = 0.f, d3 = 0.f;
#pragma unroll
            for (int q = 0; q < 16; ++q) {
                float4 h4 = slot4[q];
                d0 = fmaf(h4.x, vcol[4*q+0], d0);
                d1 = fmaf(h4.y, vcol[4*q+1], d1);
                d2 = fmaf(h4.z, vcol[4*q+2], d2);
                d3 = fmaf(h4.w, vcol[4*q+3], d3);
            }
            float dot = vb + ((d0 + d1) + (d2 + d3));
            acc = fmaf(we, fmaxf(dot, 0.f), acc);
            hvC = hvN;
        }
        // build up = elu([acc(64) | aggrE(32) | h_in[n](64)])
        myup[lane] = eluf(acc);
        if (lane < EDGEF) myup[NODE + lane] = aggrE_elu[(size_t)n * EDGEF + lane];
        myup[NODE + EDGEF + lane] = eluf(h_in[(size_t)n * NODE + lane]);
        // U-FFN: o_j = relu(sum_t up[t]*U[t][j] + Ub_j) * w_atoms[n]
        float o = ub;
#pragma unroll
        for (int t2 = 0; t2 < UPF; t2 += 2) {
            float2 u2 = *(const float2*)&myup[t2];                 // broadcast
            float2 w2 = *(const float2*)&lds_Ut[lane * UT_STRIDE + t2];
            o = fmaf(u2.x, w2.x, o);
            o = fmaf(u2.y, w2.y, o);
        }
        h_out[(size_t)n * NODE + lane] = fmaxf(o, 0.f) * watoms[n];
    }
}

// ---------------------------------------------------------------------------
__global__ void k_add4(const float4* __restrict__ a, const float4* __restrict__ b,
                       float4* __restrict__ o, int n4) {
    int i = blockIdx.x * 256 + threadIdx.x;
    if (i < n4) {
        float4 x = a[i], y = b[i];
        float4 r = { x.x + y.x, x.y + y.y, x.z + y.z, x.w + y.w };
        o[i] = r;
    }
}

// ---------------------------------------------------------------------------
// Readout GEMM y = hx @ R_W + R_b, fused BN column stats.
// Wave w owns output channels [64w,64w+64): R column in 64 VGPRs. hx row via
// lane-parallel load -> per-wave LDS slot -> uniform b128 broadcast. No R tile
// in LDS, no scalar-cache reads. Block processes a contiguous node chunk.
__global__ __launch_bounds__(256) void k_y(
    const float* __restrict__ hx, const float* __restrict__ RW,
    const float* __restrict__ Rb, float* __restrict__ y,
    float* colsum, float* colsumsq, int N, int chunk) {
    __shared__ float slot[4][NODE];
    int tid = threadIdx.x;
    int lane = tid & 63, w = tid >> 6;
    float rcol[NODE];
#pragma unroll
    for (int k = 0; k < NODE; ++k) rcol[k] = RW[k * RD + w * 64 + lane];
    float rb = Rb[w * 64 + lane];
    const float4* s4 = (const float4*)slot[w];
    float sum = 0.f, sq = 0.f;
    int n0 = blockIdx.x * chunk;
    int n1 = n0 + chunk; if (n1 > N) n1 = N;
    float hvC = (n0 < n1) ? hx[(size_t)n0 * NODE + lane] : 0.f;
    for (int n = n0; n < n1; ++n) {
        float hvN = (n + 1 < n1) ? hx[(size_t)(n + 1) * NODE + lane] : 0.f;
        slot[w][lane] = hvC;
        float d0 = 0.f, d1 = 0.f, d2 = 0.f, d3 = 0.f;
#pragma unroll
        for (int q = 0; q < 16; ++q) {
            float4 h4 = s4[q];
            d0 = fmaf(h4.x, rcol[4*q+0], d0);
            d1 = fmaf(h4.y, rcol[4*q+1], d1);
            d2 = fmaf(h4.z, rcol[4*q+2], d2);
            d3 = fmaf(h4.w, rcol[4*q+3], d3);
        }
        float v = rb + ((d0 + d1) + (d2 + d3));
        y[(size_t)n * RD + w * 64 + lane] = v;
        sum += v; sq = fmaf(v, v, sq);
        hvC = hvN;
    }
    atomicAdd(&colsum[w * 64 + lane], sum);
    atomicAdd(&colsumsq[w * 64 + lane], sq);
}

// graph boundaries from sorted batch: gstart[g] = first n with batch[n] >= g
__global__ void k_gbounds(const int* __restrict__ batch, int* gstart, int N, int G) {
    int n = blockIdx.x * 256 + threadIdx.x;
    if (n > N) return;
    int bprev = (n == 0) ? -1 : batch[n - 1];
    int bcur = (n == N) ? G : batch[n];
    for (int g = bprev + 1; g <= bcur; ++g) gstart[g] = n;
}

// BN(normalize) + relu + segment mean. block per graph, thread per channel.
__global__ void k_out(const float* __restrict__ y, const float* __restrict__ colsum,
                      const float* __restrict__ colsumsq, const float* __restrict__ gamma,
                      const float* __restrict__ beta, const int* __restrict__ gstart,
                      float* __restrict__ out, float invN) {
    int g = blockIdx.x, c = threadIdx.x;
    float mu = colsum[c] * invN;
    float var = fmaxf(colsumsq[c] * invN - mu * mu, 0.f);
    float inv = rsqrtf(var + 1e-5f);
    float ga = gamma[c], be = beta[c];
    int a = gstart[g], b = gstart[g + 1];
    float acc = 0.f;
    for (int n = a; n < b; ++n) {
        float v = y[(size_t)n * RD + c];
        acc += fmaxf(fmaf((v - mu) * inv, ga, be), 0.f);
    }
    out[(size_t)g * RD + c] = acc / fmaxf((float)(b - a), 1.f);
}

// ---------------------------------------------------------------------------
extern "C" void kernel_launch(void* const* d_in, const int* in_sizes, int n_in,
                              void* d_out, int out_size, void* d_ws, size_t ws_size,
                              hipStream_t stream) {
    const float* x      = (const float*)d_in[0];
    const int*   ei     = (const int*)d_in[1];
    const float* eattr  = (const float*)d_in[2];
    const float* watoms = (const float*)d_in[3];
    const float* wbonds = (const float*)d_in[4];
    const int*   batch  = (const int*)d_in[5];
    const float* VW = (const float*)d_in[6];
    const float* Vb = (const float*)d_in[7];
    const float* EW = (const float*)d_in[8];
    const float* Eb = (const float*)d_in[9];
    const float* UW = (const float*)d_in[10];
    const float* Ub = (const float*)d_in[11];
    const float* RW = (const float*)d_in[12];
    const float* Rb = (const float*)d_in[13];
    const float* Rg = (const float*)d_in[14];
    const float* Rbe = (const float*)d_in[15];
    float* out = (float*)d_out;

    const int N = in_sizes[0] / NODE;
    const int E = in_sizes[4];
    const int G = out_size / RD;
    const int* src = ei;
    const int* dst = ei + E;

    char* p = (char*)d_ws;
    auto alloc = [&](size_t bytes) -> char* {
        char* r = p;
        p += (bytes + 255) & ~(size_t)255;
        return r;
    };
    float* aggrE   = (float*)alloc((size_t)N * EDGEF * 4);   // stores elu(aggrE)
    int*   cnt     = (int*)alloc((size_t)N * 4);
    int*   starts  = (int*)alloc((size_t)(N + 1) * 4);
    int*   cursor  = (int*)alloc((size_t)N * 4);
    int*   bsum    = (int*)alloc(64 * 4);
    int*   boff    = (int*)alloc(64 * 4);
    int*   esrc    = (int*)alloc((size_t)E * 4);
    float* ewS     = (float*)alloc((size_t)E * 4);
    float* hA      = (float*)alloc((size_t)N * NODE * 4);    // h1, later h3
    float* hB      = (float*)alloc((size_t)N * NODE * 4);    // h2, later h4
    float* tmp     = (float*)alloc((size_t)N * NODE * 4);    // sums, later hx
    float* colstat = (float*)alloc((size_t)2 * RD * 4);
    int*   gstart  = (int*)alloc((size_t)(G + 1) * 4);
    // medge (E*32 f32 = 102MB) and ybuf (N*256 f32 = 51MB): disjoint lifetimes.
    size_t big = (size_t)E * EDGEF * 4;
    size_t ybytes = (size_t)N * RD * 4;
    float* medge   = (float*)alloc(big > ybytes ? big : ybytes);
    float* ybuf    = medge;

    hipMemsetAsync(cnt, 0, (size_t)N * 4, stream);
    hipMemsetAsync(colstat, 0, (size_t)2 * RD * 4, stream);

    int eblocks = (E + 255) / 256;
    int sblocks = (N + 1023) / 1024;

    k_count<<<eblocks, 256, 0, stream>>>(dst, cnt, E);
    k_scanA<<<sblocks, 256, 0, stream>>>(cnt, starts, bsum, N);
    k_scanB<<<1, 64, 0, stream>>>(bsum, boff, sblocks, starts, N);
    k_scanC<<<(N + 255) / 256, 256, 0, stream>>>(boff, starts, cursor, N);
    k_fill_mij<<<eblocks, 256, 0, stream>>>(eattr, src, dst, wbonds, EW, Eb,
                                            cursor, esrc, ewS, medge, E);
    k_aggrE<<<1024, 256, 0, stream>>>(medge, starts, aggrE, N);

    int n4 = N * NODE / 4;
    int ablocks = (n4 + 255) / 256;

    // depth 0: h1 = mp(x)
    k_node<<<768, 512, 0, stream>>>(x, hA, starts, esrc, ewS, aggrE, VW, Vb, UW, Ub, watoms, N);
    // depth 1: h2 = mp(h1)
    k_node<<<768, 512, 0, stream>>>(hA, hB, starts, esrc, ewS, aggrE, VW, Vb, UW, Ub, watoms, N);
    // depth 2: h3 = mp(h1 + h2)
    k_add4<<<ablocks, 256, 0, stream>>>((const float4*)hA, (const float4*)hB, (float4*)tmp, n4);
    k_node<<<768, 512, 0, stream>>>(tmp, hA, starts, esrc, ewS, aggrE, VW, Vb, UW, Ub, watoms, N);
    // depth 3: h4 = mp(h2 + h3)
    k_add4<<<ablocks, 256, 0, stream>>>((const float4*)hB, (const float4*)hA, (float4*)tmp, n4);
    k_node<<<768, 512, 0, stream>>>(tmp, hB, starts, esrc, ewS, aggrE, VW, Vb, UW, Ub, watoms, N);

    // readout: hx = h4 + x (into tmp)
    k_add4<<<ablocks, 256, 0, stream>>>((const float4*)hB, (const float4*)x, (float4*)tmp, n4);
    int yblocks = 512;
    int chunk = (N + yblocks - 1) / yblocks;
    k_y<<<yblocks, 256, 0, stream>>>(tmp, RW, Rb, ybuf, colstat, colstat + RD, N, chunk);
    k_gbounds<<<(N + 256) / 256, 256, 0, stream>>>(batch, gstart, N, G);
    k_out<<<G, RD, 0, stream>>>(ybuf, colstat, colstat + RD, Rg, Rbe, gstart, out, 1.0f / (float)N);
}

// Round 5
// 2608.190 us; speedup vs baseline: 1.1242x; 1.1242x over previous
//
#include <hip/hip_runtime.h>
#include <cstdint>
#include <cstddef>

#define NODE 64
#define EDGEF 32
#define UPF 160   // 2*NODE + EDGEF
#define RD 256
#define UT_STRIDE 162  // 160 padded: float2 reads -> 2-way bank aliasing (free)

__device__ __forceinline__ float eluf(float x) { return x > 0.f ? x : expm1f(x); }

// ---------------------------------------------------------------------------
// CSR build
__global__ void k_count(const int* __restrict__ dst, int* cnt, int E) {
    int e = blockIdx.x * 256 + threadIdx.x;
    if (e < E) atomicAdd(&cnt[dst[e]], 1);
}

__global__ void k_scanA(const int* __restrict__ cnt, int* starts, int* bsum, int N) {
    __shared__ int sh[256];
    int t = threadIdx.x;
    int base = blockIdx.x * 1024 + t * 4;
    int v0 = 0, v1 = 0, v2 = 0, v3 = 0;
    if (base + 0 < N) v0 = cnt[base + 0];
    if (base + 1 < N) v1 = cnt[base + 1];
    if (base + 2 < N) v2 = cnt[base + 2];
    if (base + 3 < N) v3 = cnt[base + 3];
    int tot = v0 + v1 + v2 + v3;
    sh[t] = tot;
    __syncthreads();
    for (int off = 1; off < 256; off <<= 1) {
        int add = (t >= off) ? sh[t - off] : 0;
        __syncthreads();
        sh[t] += add;
        __syncthreads();
    }
    int excl = sh[t] - tot;
    if (base + 0 < N) starts[base + 0] = excl;
    if (base + 1 < N) starts[base + 1] = excl + v0;
    if (base + 2 < N) starts[base + 2] = excl + v0 + v1;
    if (base + 3 < N) starts[base + 3] = excl + v0 + v1 + v2;
    if (t == 255) bsum[blockIdx.x] = sh[255];
}

__global__ void k_scanB(const int* __restrict__ bsum, int* boff, int nb, int* starts, int N) {
    if (threadIdx.x == 0 && blockIdx.x == 0) {
        int run = 0;
        for (int b = 0; b < nb; ++b) { boff[b] = run; run += bsum[b]; }
        starts[N] = run;
    }
}

__global__ void k_scanC(const int* __restrict__ boff, int* starts, int* cursor, int N) {
    int i = blockIdx.x * 256 + threadIdx.x;
    if (i < N) {
        int v = starts[i] + boff[i >> 10];
        starts[i] = v;
        cursor[i] = v;
    }
}

// ---------------------------------------------------------------------------
// Fused CSR-fill + edge FFN: per edge compute w_bond * relu(ea@E_W + E_b),
// write contiguous 128B row into medge[pos] (CSR slot). No float atomics.
__global__ void k_fill_mij(const float* __restrict__ ea, const int* __restrict__ src,
                           const int* __restrict__ dst, const float* __restrict__ wb,
                           const float* __restrict__ EW, const float* __restrict__ Eb,
                           int* cursor, int* esrc, float* ewS, float* medge, int E) {
    __shared__ float ew_s[EDGEF * EDGEF];
    __shared__ float eb_s[EDGEF];
    int tid = threadIdx.x;
    for (int i = tid; i < EDGEF * EDGEF; i += 256) ew_s[i] = EW[i];
    if (tid < EDGEF) eb_s[tid] = Eb[tid];
    __syncthreads();
    int e = blockIdx.x * 256 + tid;
    if (e >= E) return;
    float a[EDGEF];
    const float4* row = (const float4*)(ea + (size_t)e * EDGEF);
#pragma unroll
    for (int q = 0; q < 8; ++q) {
        float4 v = row[q];
        a[4*q] = v.x; a[4*q+1] = v.y; a[4*q+2] = v.z; a[4*q+3] = v.w;
    }
    float m[EDGEF];
#pragma unroll
    for (int j = 0; j < EDGEF; ++j) m[j] = eb_s[j];
#pragma unroll
    for (int k = 0; k < EDGEF; ++k) {
        float ak = a[k];
#pragma unroll
        for (int j = 0; j < EDGEF; ++j) m[j] = fmaf(ak, ew_s[k*EDGEF + j], m[j]);
    }
    float w = wb[e];
    int pos = atomicAdd(&cursor[dst[e]], 1);
    esrc[pos] = src[e];
    ewS[pos] = w;
    float4* mp = (float4*)(medge + (size_t)pos * EDGEF);
#pragma unroll
    for (int q = 0; q < 8; ++q) {
        float4 v = { w * fmaxf(m[4*q], 0.f),   w * fmaxf(m[4*q+1], 0.f),
                     w * fmaxf(m[4*q+2], 0.f), w * fmaxf(m[4*q+3], 0.f) };
        mp[q] = v;
    }
}

// ---------------------------------------------------------------------------
// aggrE[n] = elu( sum_{edges->n} medge[i] )  -- sequential coalesced reads.
__global__ __launch_bounds__(256) void k_aggrE(const float* __restrict__ medge,
                                               const int* __restrict__ starts,
                                               float* __restrict__ aggrE_elu, int N) {
    int tid = threadIdx.x;
    int lane = tid & 63, wid = tid >> 6;
    int half = lane >> 5, ch = lane & 31;
    int nwaves = gridDim.x * 4;
    for (int n = blockIdx.x * 4 + wid; n < N; n += nwaves) {
        int s0 = starts[n], s1 = starts[n + 1];
        float acc = 0.f;
        for (int i = s0 + half; i < s1; i += 2)
            acc += medge[(size_t)i * EDGEF + ch];
        acc += __shfl_xor(acc, 32, 64);
        if (lane < EDGEF) aggrE_elu[(size_t)n * EDGEF + lane] = eluf(acc);
    }
}

// ---------------------------------------------------------------------------
// Fused message-passing depth. Wave per node; lane j owns channel j.
// Gather path: lane-parallel vector load of h[src] row (256B coalesced,
// pipelined 1 edge ahead in a register) -> per-wave LDS slot -> 16 uniform
// ds_read_b128 broadcasts against V column held in VGPRs.
// launch_bounds(512,4): 128-VGPR budget so vcol[64] stays in registers
// (at (512,6)=80 VGPRs the compiler spilled vcol to scratch: 12.8GB/depth
// of scratch traffic, VGPR_Count=40, WRITE_SIZE 198MB -- round 4 lesson).
__global__ __launch_bounds__(512, 4) void k_node(
    const float* __restrict__ h_in, float* __restrict__ h_out,
    const int* __restrict__ starts, const int* __restrict__ esrc,
    const float* __restrict__ ewS, const float* __restrict__ aggrE_elu,
    const float* __restrict__ VW, const float* __restrict__ Vb,
    const float* __restrict__ UW, const float* __restrict__ Ub,
    const float* __restrict__ watoms, int N) {
    __shared__ float lds_Ut[NODE * UT_STRIDE];   // 41.4 KB
    __shared__ float lds_up[8 * UPF];            // 5 KB
    __shared__ float lds_slot[8 * NODE];         // 2 KB: per-wave gather slot
    int tid = threadIdx.x;
    for (int idx = tid; idx < UPF * NODE; idx += 512) {
        int j = idx & 63, t2 = idx >> 6;
        lds_Ut[j * UT_STRIDE + t2] = UW[idx];
    }
    int lane = tid & 63, wid = tid >> 6;
    float vcol[NODE];
#pragma unroll
    for (int k = 0; k < NODE; ++k) vcol[k] = VW[k * NODE + lane];
    float vb = Vb[lane];
    float ub = Ub[lane];
    __syncthreads();
    float* myup = lds_up + wid * UPF;
    float* slot = lds_slot + wid * NODE;
    const float4* slot4 = (const float4*)slot;
    int nwaves = gridDim.x * 8;
    for (int n = blockIdx.x * 8 + wid; n < N; n += nwaves) {
        int s0 = starts[n], s1 = starts[n + 1];
        int deg = s1 - s0;
        float acc = 0.f;
        // register-carried prefetch of the gathered row (vector loads)
        float hvC = 0.f;
        if (deg > 0) {
            int sidx0 = esrc[s0];
            hvC = h_in[(size_t)sidx0 * NODE + lane];
        }
        for (int i = 0; i < deg; ++i) {
            // issue next row load (stays in flight during compute)
            float hvN = 0.f;
            if (i + 1 < deg) {
                int sidxN = esrc[s0 + i + 1];
                hvN = h_in[(size_t)sidxN * NODE + lane];
            }
            float we = ewS[s0 + i];
            slot[lane] = hvC;                       // waits only on hvC
            // dot from uniform b128 broadcasts (conflict-free)
            float d0 = 0.f, d1 = 0.f, d2 = 0.f, d3 = 0.f;
#pragma unroll
            for (int q = 0; q < 16; ++q) {
                float4 h4 = slot4[q];
                d0 = fmaf(h4.x, vcol[4*q+0], d0);
                d1 = fmaf(h4.y, vcol[4*q+1], d1);
                d2 = fmaf(h4.z, vcol[4*q+2], d2);
                d3 = fmaf(h4.w, vcol[4*q+3], d3);
            }
            float dot = vb + ((d0 + d1) + (d2 + d3));
            acc = fmaf(we, fmaxf(dot, 0.f), acc);
            hvC = hvN;
        }
        // build up = elu([acc(64) | aggrE(32) | h_in[n](64)])
        myup[lane] = eluf(acc);
        if (lane < EDGEF) myup[NODE + lane] = aggrE_elu[(size_t)n * EDGEF + lane];
        myup[NODE + EDGEF + lane] = eluf(h_in[(size_t)n * NODE + lane]);
        // U-FFN: o_j = relu(sum_t up[t]*U[t][j] + Ub_j) * w_atoms[n]
        float o = ub;
#pragma unroll
        for (int t2 = 0; t2 < UPF; t2 += 2) {
            float2 u2 = *(const float2*)&myup[t2];                 // broadcast
            float2 w2 = *(const float2*)&lds_Ut[lane * UT_STRIDE + t2];
            o = fmaf(u2.x, w2.x, o);
            o = fmaf(u2.y, w2.y, o);
        }
        h_out[(size_t)n * NODE + lane] = fmaxf(o, 0.f) * watoms[n];
    }
}

// ---------------------------------------------------------------------------
__global__ void k_add4(const float4* __restrict__ a, const float4* __restrict__ b,
                       float4* __restrict__ o, int n4) {
    int i = blockIdx.x * 256 + threadIdx.x;
    if (i < n4) {
        float4 x = a[i], y = b[i];
        float4 r = { x.x + y.x, x.y + y.y, x.z + y.z, x.w + y.w };
        o[i] = r;
    }
}

// ---------------------------------------------------------------------------
// Readout GEMM y = hx @ R_W + R_b, fused BN column stats.
// Wave w owns output channels [64w,64w+64): R column in 64 VGPRs. hx row via
// lane-parallel load -> per-wave LDS slot -> uniform b128 broadcast.
__global__ __launch_bounds__(256) void k_y(
    const float* __restrict__ hx, const float* __restrict__ RW,
    const float* __restrict__ Rb, float* __restrict__ y,
    float* colsum, float* colsumsq, int N, int chunk) {
    __shared__ float slot[4][NODE];
    int tid = threadIdx.x;
    int lane = tid & 63, w = tid >> 6;
    float rcol[NODE];
#pragma unroll
    for (int k = 0; k < NODE; ++k) rcol[k] = RW[k * RD + w * 64 + lane];
    float rb = Rb[w * 64 + lane];
    const float4* s4 = (const float4*)slot[w];
    float sum = 0.f, sq = 0.f;
    int n0 = blockIdx.x * chunk;
    int n1 = n0 + chunk; if (n1 > N) n1 = N;
    float hvC = (n0 < n1) ? hx[(size_t)n0 * NODE + lane] : 0.f;
    for (int n = n0; n < n1; ++n) {
        float hvN = (n + 1 < n1) ? hx[(size_t)(n + 1) * NODE + lane] : 0.f;
        slot[w][lane] = hvC;
        float d0 = 0.f, d1 = 0.f, d2 = 0.f, d3 = 0.f;
#pragma unroll
        for (int q = 0; q < 16; ++q) {
            float4 h4 = s4[q];
            d0 = fmaf(h4.x, rcol[4*q+0], d0);
            d1 = fmaf(h4.y, rcol[4*q+1], d1);
            d2 = fmaf(h4.z, rcol[4*q+2], d2);
            d3 = fmaf(h4.w, rcol[4*q+3], d3);
        }
        float v = rb + ((d0 + d1) + (d2 + d3));
        y[(size_t)n * RD + w * 64 + lane] = v;
        sum += v; sq = fmaf(v, v, sq);
        hvC = hvN;
    }
    atomicAdd(&colsum[w * 64 + lane], sum);
    atomicAdd(&colsumsq[w * 64 + lane], sq);
}

// graph boundaries from sorted batch: gstart[g] = first n with batch[n] >= g
__global__ void k_gbounds(const int* __restrict__ batch, int* gstart, int N, int G) {
    int n = blockIdx.x * 256 + threadIdx.x;
    if (n > N) return;
    int bprev = (n == 0) ? -1 : batch[n - 1];
    int bcur = (n == N) ? G : batch[n];
    for (int g = bprev + 1; g <= bcur; ++g) gstart[g] = n;
}

// BN(normalize) + relu + segment mean. block per graph, thread per channel.
__global__ void k_out(const float* __restrict__ y, const float* __restrict__ colsum,
                      const float* __restrict__ colsumsq, const float* __restrict__ gamma,
                      const float* __restrict__ beta, const int* __restrict__ gstart,
                      float* __restrict__ out, float invN) {
    int g = blockIdx.x, c = threadIdx.x;
    float mu = colsum[c] * invN;
    float var = fmaxf(colsumsq[c] * invN - mu * mu, 0.f);
    float inv = rsqrtf(var + 1e-5f);
    float ga = gamma[c], be = beta[c];
    int a = gstart[g], b = gstart[g + 1];
    float acc = 0.f;
    for (int n = a; n < b; ++n) {
        float v = y[(size_t)n * RD + c];
        acc += fmaxf(fmaf((v - mu) * inv, ga, be), 0.f);
    }
    out[(size_t)g * RD + c] = acc / fmaxf((float)(b - a), 1.f);
}

// ---------------------------------------------------------------------------
extern "C" void kernel_launch(void* const* d_in, const int* in_sizes, int n_in,
                              void* d_out, int out_size, void* d_ws, size_t ws_size,
                              hipStream_t stream) {
    const float* x      = (const float*)d_in[0];
    const int*   ei     = (const int*)d_in[1];
    const float* eattr  = (const float*)d_in[2];
    const float* watoms = (const float*)d_in[3];
    const float* wbonds = (const float*)d_in[4];
    const int*   batch  = (const int*)d_in[5];
    const float* VW = (const float*)d_in[6];
    const float* Vb = (const float*)d_in[7];
    const float* EW = (const float*)d_in[8];
    const float* Eb = (const float*)d_in[9];
    const float* UW = (const float*)d_in[10];
    const float* Ub = (const float*)d_in[11];
    const float* RW = (const float*)d_in[12];
    const float* Rb = (const float*)d_in[13];
    const float* Rg = (const float*)d_in[14];
    const float* Rbe = (const float*)d_in[15];
    float* out = (float*)d_out;

    const int N = in_sizes[0] / NODE;
    const int E = in_sizes[4];
    const int G = out_size / RD;
    const int* src = ei;
    const int* dst = ei + E;

    char* p = (char*)d_ws;
    auto alloc = [&](size_t bytes) -> char* {
        char* r = p;
        p += (bytes + 255) & ~(size_t)255;
        return r;
    };
    float* aggrE   = (float*)alloc((size_t)N * EDGEF * 4);   // stores elu(aggrE)
    int*   cnt     = (int*)alloc((size_t)N * 4);
    int*   starts  = (int*)alloc((size_t)(N + 1) * 4);
    int*   cursor  = (int*)alloc((size_t)N * 4);
    int*   bsum    = (int*)alloc(64 * 4);
    int*   boff    = (int*)alloc(64 * 4);
    int*   esrc    = (int*)alloc((size_t)E * 4);
    float* ewS     = (float*)alloc((size_t)E * 4);
    float* hA      = (float*)alloc((size_t)N * NODE * 4);    // h1, later h3
    float* hB      = (float*)alloc((size_t)N * NODE * 4);    // h2, later h4
    float* tmp     = (float*)alloc((size_t)N * NODE * 4);    // sums, later hx
    float* colstat = (float*)alloc((size_t)2 * RD * 4);
    int*   gstart  = (int*)alloc((size_t)(G + 1) * 4);
    // medge (E*32 f32 = 102MB) and ybuf (N*256 f32 = 51MB): disjoint lifetimes.
    size_t big = (size_t)E * EDGEF * 4;
    size_t ybytes = (size_t)N * RD * 4;
    float* medge   = (float*)alloc(big > ybytes ? big : ybytes);
    float* ybuf    = medge;

    hipMemsetAsync(cnt, 0, (size_t)N * 4, stream);
    hipMemsetAsync(colstat, 0, (size_t)2 * RD * 4, stream);

    int eblocks = (E + 255) / 256;
    int sblocks = (N + 1023) / 1024;

    k_count<<<eblocks, 256, 0, stream>>>(dst, cnt, E);
    k_scanA<<<sblocks, 256, 0, stream>>>(cnt, starts, bsum, N);
    k_scanB<<<1, 64, 0, stream>>>(bsum, boff, sblocks, starts, N);
    k_scanC<<<(N + 255) / 256, 256, 0, stream>>>(boff, starts, cursor, N);
    k_fill_mij<<<eblocks, 256, 0, stream>>>(eattr, src, dst, wbonds, EW, Eb,
                                            cursor, esrc, ewS, medge, E);
    k_aggrE<<<1024, 256, 0, stream>>>(medge, starts, aggrE, N);

    int n4 = N * NODE / 4;
    int ablocks = (n4 + 255) / 256;

    // depth 0: h1 = mp(x)
    k_node<<<768, 512, 0, stream>>>(x, hA, starts, esrc, ewS, aggrE, VW, Vb, UW, Ub, watoms, N);
    // depth 1: h2 = mp(h1)
    k_node<<<768, 512, 0, stream>>>(hA, hB, starts, esrc, ewS, aggrE, VW, Vb, UW, Ub, watoms, N);
    // depth 2: h3 = mp(h1 + h2)
    k_add4<<<ablocks, 256, 0, stream>>>((const float4*)hA, (const float4*)hB, (float4*)tmp, n4);
    k_node<<<768, 512, 0, stream>>>(tmp, hA, starts, esrc, ewS, aggrE, VW, Vb, UW, Ub, watoms, N);
    // depth 3: h4 = mp(h2 + h3)
    k_add4<<<ablocks, 256, 0, stream>>>((const float4*)hB, (const float4*)hA, (float4*)tmp, n4);
    k_node<<<768, 512, 0, stream>>>(tmp, hB, starts, esrc, ewS, aggrE, VW, Vb, UW, Ub, watoms, N);

    // readout: hx = h4 + x (into tmp)
    k_add4<<<ablocks, 256, 0, stream>>>((const float4*)hB, (const float4*)x, (float4*)tmp, n4);
    int yblocks = 512;
    int chunk = (N + yblocks - 1) / yblocks;
    k_y<<<yblocks, 256, 0, stream>>>(tmp, RW, Rb, ybuf, colstat, colstat + RD, N, chunk);
    k_gbounds<<<(N + 256) / 256, 256, 0, stream>>>(batch, gstart, N, G);
    k_out<<<G, RD, 0, stream>>>(ybuf, colstat, colstat + RD, Rg, Rbe, gstart, out, 1.0f / (float)N);
}

// Round 6
// 1304.590 us; speedup vs baseline: 2.2476x; 1.9992x over previous
//
#include <hip/hip_runtime.h>
#include <cstdint>
#include <cstddef>

#define NODE 64
#define EDGEF 32
#define UPF 160   // 2*NODE + EDGEF
#define RD 256
#define UT_STRIDE 162  // 160 padded: float2 reads -> 2-way bank aliasing (free)

__device__ __forceinline__ float eluf(float x) { return x > 0.f ? x : expm1f(x); }

// ---------------------------------------------------------------------------
// CSR build
__global__ void k_count(const int* __restrict__ dst, int* cnt, int E) {
    int e = blockIdx.x * 256 + threadIdx.x;
    if (e < E) atomicAdd(&cnt[dst[e]], 1);
}

__global__ void k_scanA(const int* __restrict__ cnt, int* starts, int* bsum, int N) {
    __shared__ int sh[256];
    int t = threadIdx.x;
    int base = blockIdx.x * 1024 + t * 4;
    int v0 = 0, v1 = 0, v2 = 0, v3 = 0;
    if (base + 0 < N) v0 = cnt[base + 0];
    if (base + 1 < N) v1 = cnt[base + 1];
    if (base + 2 < N) v2 = cnt[base + 2];
    if (base + 3 < N) v3 = cnt[base + 3];
    int tot = v0 + v1 + v2 + v3;
    sh[t] = tot;
    __syncthreads();
    for (int off = 1; off < 256; off <<= 1) {
        int add = (t >= off) ? sh[t - off] : 0;
        __syncthreads();
        sh[t] += add;
        __syncthreads();
    }
    int excl = sh[t] - tot;
    if (base + 0 < N) starts[base + 0] = excl;
    if (base + 1 < N) starts[base + 1] = excl + v0;
    if (base + 2 < N) starts[base + 2] = excl + v0 + v1;
    if (base + 3 < N) starts[base + 3] = excl + v0 + v1 + v2;
    if (t == 255) bsum[blockIdx.x] = sh[255];
}

__global__ void k_scanB(const int* __restrict__ bsum, int* boff, int nb, int* starts, int N) {
    if (threadIdx.x == 0 && blockIdx.x == 0) {
        int run = 0;
        for (int b = 0; b < nb; ++b) { boff[b] = run; run += bsum[b]; }
        starts[N] = run;
    }
}

__global__ void k_scanC(const int* __restrict__ boff, int* starts, int* cursor, int N) {
    int i = blockIdx.x * 256 + threadIdx.x;
    if (i < N) {
        int v = starts[i] + boff[i >> 10];
        starts[i] = v;
        cursor[i] = v;
    }
}

// ---------------------------------------------------------------------------
// Fused CSR-fill + edge FFN: per edge compute w_bond * relu(ea@E_W + E_b),
// write contiguous 128B row into medge[pos] (CSR slot). No float atomics.
__global__ void k_fill_mij(const float* __restrict__ ea, const int* __restrict__ src,
                           const int* __restrict__ dst, const float* __restrict__ wb,
                           const float* __restrict__ EW, const float* __restrict__ Eb,
                           int* cursor, int* esrc, float* ewS, float* medge, int E) {
    __shared__ float ew_s[EDGEF * EDGEF];
    __shared__ float eb_s[EDGEF];
    int tid = threadIdx.x;
    for (int i = tid; i < EDGEF * EDGEF; i += 256) ew_s[i] = EW[i];
    if (tid < EDGEF) eb_s[tid] = Eb[tid];
    __syncthreads();
    int e = blockIdx.x * 256 + tid;
    if (e >= E) return;
    float a[EDGEF];
    const float4* row = (const float4*)(ea + (size_t)e * EDGEF);
#pragma unroll
    for (int q = 0; q < 8; ++q) {
        float4 v = row[q];
        a[4*q] = v.x; a[4*q+1] = v.y; a[4*q+2] = v.z; a[4*q+3] = v.w;
    }
    float m[EDGEF];
#pragma unroll
    for (int j = 0; j < EDGEF; ++j) m[j] = eb_s[j];
#pragma unroll
    for (int k = 0; k < EDGEF; ++k) {
        float ak = a[k];
#pragma unroll
        for (int j = 0; j < EDGEF; ++j) m[j] = fmaf(ak, ew_s[k*EDGEF + j], m[j]);
    }
    float w = wb[e];
    int pos = atomicAdd(&cursor[dst[e]], 1);
    esrc[pos] = src[e];
    ewS[pos] = w;
    float4* mp = (float4*)(medge + (size_t)pos * EDGEF);
#pragma unroll
    for (int q = 0; q < 8; ++q) {
        float4 v = { w * fmaxf(m[4*q], 0.f),   w * fmaxf(m[4*q+1], 0.f),
                     w * fmaxf(m[4*q+2], 0.f), w * fmaxf(m[4*q+3], 0.f) };
        mp[q] = v;
    }
}

// ---------------------------------------------------------------------------
// aggrE[n] = elu( sum_{edges->n} medge[i] )  -- sequential coalesced reads.
__global__ __launch_bounds__(256) void k_aggrE(const float* __restrict__ medge,
                                               const int* __restrict__ starts,
                                               float* __restrict__ aggrE_elu, int N) {
    int tid = threadIdx.x;
    int lane = tid & 63, wid = tid >> 6;
    int half = lane >> 5, ch = lane & 31;
    int nwaves = gridDim.x * 4;
    for (int n = blockIdx.x * 4 + wid; n < N; n += nwaves) {
        int s0 = starts[n], s1 = starts[n + 1];
        float acc = 0.f;
        for (int i = s0 + half; i < s1; i += 2)
            acc += medge[(size_t)i * EDGEF + ch];
        acc += __shfl_xor(acc, 32, 64);
        if (lane < EDGEF) aggrE_elu[(size_t)n * EDGEF + lane] = eluf(acc);
    }
}

// ---------------------------------------------------------------------------
// hv = relu((ha [+ hb]) @ V_W + V_b)  -- dense per-node transform, done ONCE
// per depth so the edge loop becomes a pure gather of precomputed rows.
// Wave-per-node-set; V column in 64 VGPRs; row broadcast via per-wave LDS slot.
__global__ __launch_bounds__(256) void k_hv(
    const float* __restrict__ ha, const float* __restrict__ hb, int addB,
    const float* __restrict__ VW, const float* __restrict__ Vb,
    float* __restrict__ hv, int N, int chunk) {
    __shared__ float slot[4][NODE];
    int tid = threadIdx.x;
    int lane = tid & 63, w = tid >> 6;
    float vcol[NODE];
#pragma unroll
    for (int k = 0; k < NODE; ++k) vcol[k] = VW[k * NODE + lane];
    float vb = Vb[lane];
    const float4* s4 = (const float4*)slot[w];
    int n0 = blockIdx.x * chunk;
    int n1 = n0 + chunk; if (n1 > N) n1 = N;
    for (int n = n0 + w; n < n1; n += 4) {
        float hrow = ha[(size_t)n * NODE + lane];
        if (addB) hrow += hb[(size_t)n * NODE + lane];
        slot[w][lane] = hrow;
        float d0 = 0.f, d1 = 0.f, d2 = 0.f, d3 = 0.f;
#pragma unroll
        for (int q = 0; q < 16; ++q) {
            float4 h4 = s4[q];
            d0 = fmaf(h4.x, vcol[4*q+0], d0);
            d1 = fmaf(h4.y, vcol[4*q+1], d1);
            d2 = fmaf(h4.z, vcol[4*q+2], d2);
            d3 = fmaf(h4.w, vcol[4*q+3], d3);
        }
        hv[(size_t)n * NODE + lane] = fmaxf(vb + ((d0 + d1) + (d2 + d3)), 0.f);
    }
}

// ---------------------------------------------------------------------------
// Message-passing depth, gather form: aggr[n] = sum_e w_e * hv[src_e] then
// up = elu([aggr | aggrE | h_n]) and the U-FFN. Per edge-lane: one coalesced
// 256B row load + one fma (2-deep prefetch). No big VGPR arrays -> no spill.
// In-place h update is legal: gather reads hv, each node touches only its row.
__global__ __launch_bounds__(512, 4) void k_node(
    const float* __restrict__ ha, const float* __restrict__ hb, int addB,
    const float* __restrict__ hv,
    const int* __restrict__ starts, const int* __restrict__ esrc,
    const float* __restrict__ ewS, const float* __restrict__ aggrE_elu,
    const float* __restrict__ UW, const float* __restrict__ Ub,
    const float* __restrict__ watoms, float* __restrict__ h_out, int N) {
    __shared__ float lds_Ut[NODE * UT_STRIDE];   // 41.4 KB
    __shared__ float lds_up[8 * UPF];            // 5 KB
    int tid = threadIdx.x;
    for (int idx = tid; idx < UPF * NODE; idx += 512) {
        int j = idx & 63, t2 = idx >> 6;
        lds_Ut[j * UT_STRIDE + t2] = UW[idx];
    }
    int lane = tid & 63, wid = tid >> 6;
    float ub = Ub[lane];
    __syncthreads();
    float* myup = lds_up + wid * UPF;
    int nwaves = gridDim.x * 8;
    for (int n = blockIdx.x * 8 + wid; n < N; n += nwaves) {
        int s0 = starts[n], s1 = starts[n + 1];
        int deg = s1 - s0;
        float acc = 0.f;
        float r0 = 0.f, r1 = 0.f;
        if (deg > 0) r0 = hv[(size_t)esrc[s0] * NODE + lane];
        if (deg > 1) r1 = hv[(size_t)esrc[s0 + 1] * NODE + lane];
        for (int i = 0; i < deg; ++i) {
            float rN = 0.f;
            if (i + 2 < deg) rN = hv[(size_t)esrc[s0 + i + 2] * NODE + lane];
            acc = fmaf(ewS[s0 + i], r0, acc);
            r0 = r1; r1 = rN;
        }
        // up = elu([acc(64) | aggrE(32) | h_n(64)])
        myup[lane] = eluf(acc);
        if (lane < EDGEF) myup[NODE + lane] = aggrE_elu[(size_t)n * EDGEF + lane];
        float hrow = ha[(size_t)n * NODE + lane];
        if (addB) hrow += hb[(size_t)n * NODE + lane];
        myup[NODE + EDGEF + lane] = eluf(hrow);
        // U-FFN: o_j = relu(sum_t up[t]*U[t][j] + Ub_j) * w_atoms[n]
        float o = ub;
#pragma unroll
        for (int t2 = 0; t2 < UPF; t2 += 2) {
            float2 u2 = *(const float2*)&myup[t2];                 // broadcast
            float2 w2 = *(const float2*)&lds_Ut[lane * UT_STRIDE + t2];
            o = fmaf(u2.x, w2.x, o);
            o = fmaf(u2.y, w2.y, o);
        }
        h_out[(size_t)n * NODE + lane] = fmaxf(o, 0.f) * watoms[n];
    }
}

// ---------------------------------------------------------------------------
// Readout GEMM y = (ha+hb) @ R_W + R_b, fused BN column stats.
// Wave w owns output channels [64w,64w+64): R column in 64 VGPRs.
__global__ __launch_bounds__(256) void k_y(
    const float* __restrict__ ha, const float* __restrict__ hb,
    const float* __restrict__ RW, const float* __restrict__ Rb,
    float* __restrict__ y, float* colsum, float* colsumsq, int N, int chunk) {
    __shared__ float slot[4][NODE];
    int tid = threadIdx.x;
    int lane = tid & 63, w = tid >> 6;
    float rcol[NODE];
#pragma unroll
    for (int k = 0; k < NODE; ++k) rcol[k] = RW[k * RD + w * 64 + lane];
    float rb = Rb[w * 64 + lane];
    const float4* s4 = (const float4*)slot[w];
    float sum = 0.f, sq = 0.f;
    int n0 = blockIdx.x * chunk;
    int n1 = n0 + chunk; if (n1 > N) n1 = N;
    for (int n = n0; n < n1; ++n) {
        float hvC = ha[(size_t)n * NODE + lane] + hb[(size_t)n * NODE + lane];
        slot[w][lane] = hvC;
        float d0 = 0.f, d1 = 0.f, d2 = 0.f, d3 = 0.f;
#pragma unroll
        for (int q = 0; q < 16; ++q) {
            float4 h4 = s4[q];
            d0 = fmaf(h4.x, rcol[4*q+0], d0);
            d1 = fmaf(h4.y, rcol[4*q+1], d1);
            d2 = fmaf(h4.z, rcol[4*q+2], d2);
            d3 = fmaf(h4.w, rcol[4*q+3], d3);
        }
        float v = rb + ((d0 + d1) + (d2 + d3));
        y[(size_t)n * RD + w * 64 + lane] = v;
        sum += v; sq = fmaf(v, v, sq);
    }
    atomicAdd(&colsum[w * 64 + lane], sum);
    atomicAdd(&colsumsq[w * 64 + lane], sq);
}

// graph boundaries from sorted batch: gstart[g] = first n with batch[n] >= g
__global__ void k_gbounds(const int* __restrict__ batch, int* gstart, int N, int G) {
    int n = blockIdx.x * 256 + threadIdx.x;
    if (n > N) return;
    int bprev = (n == 0) ? -1 : batch[n - 1];
    int bcur = (n == N) ? G : batch[n];
    for (int g = bprev + 1; g <= bcur; ++g) gstart[g] = n;
}

// BN(normalize) + relu + segment mean. block per graph, thread per channel.
__global__ void k_out(const float* __restrict__ y, const float* __restrict__ colsum,
                      const float* __restrict__ colsumsq, const float* __restrict__ gamma,
                      const float* __restrict__ beta, const int* __restrict__ gstart,
                      float* __restrict__ out, float invN) {
    int g = blockIdx.x, c = threadIdx.x;
    float mu = colsum[c] * invN;
    float var = fmaxf(colsumsq[c] * invN - mu * mu, 0.f);
    float inv = rsqrtf(var + 1e-5f);
    float ga = gamma[c], be = beta[c];
    int a = gstart[g], b = gstart[g + 1];
    float acc = 0.f;
    for (int n = a; n < b; ++n) {
        float v = y[(size_t)n * RD + c];
        acc += fmaxf(fmaf((v - mu) * inv, ga, be), 0.f);
    }
    out[(size_t)g * RD + c] = acc / fmaxf((float)(b - a), 1.f);
}

// ---------------------------------------------------------------------------
extern "C" void kernel_launch(void* const* d_in, const int* in_sizes, int n_in,
                              void* d_out, int out_size, void* d_ws, size_t ws_size,
                              hipStream_t stream) {
    const float* x      = (const float*)d_in[0];
    const int*   ei     = (const int*)d_in[1];
    const float* eattr  = (const float*)d_in[2];
    const float* watoms = (const float*)d_in[3];
    const float* wbonds = (const float*)d_in[4];
    const int*   batch  = (const int*)d_in[5];
    const float* VW = (const float*)d_in[6];
    const float* Vb = (const float*)d_in[7];
    const float* EW = (const float*)d_in[8];
    const float* Eb = (const float*)d_in[9];
    const float* UW = (const float*)d_in[10];
    const float* Ub = (const float*)d_in[11];
    const float* RW = (const float*)d_in[12];
    const float* Rb = (const float*)d_in[13];
    const float* Rg = (const float*)d_in[14];
    const float* Rbe = (const float*)d_in[15];
    float* out = (float*)d_out;

    const int N = in_sizes[0] / NODE;
    const int E = in_sizes[4];
    const int G = out_size / RD;
    const int* src = ei;
    const int* dst = ei + E;

    char* p = (char*)d_ws;
    auto alloc = [&](size_t bytes) -> char* {
        char* r = p;
        p += (bytes + 255) & ~(size_t)255;
        return r;
    };
    float* aggrE   = (float*)alloc((size_t)N * EDGEF * 4);   // stores elu(aggrE)
    int*   cnt     = (int*)alloc((size_t)N * 4);
    int*   starts  = (int*)alloc((size_t)(N + 1) * 4);
    int*   cursor  = (int*)alloc((size_t)N * 4);
    int*   bsum    = (int*)alloc(64 * 4);
    int*   boff    = (int*)alloc(64 * 4);
    int*   esrc    = (int*)alloc((size_t)E * 4);
    float* ewS     = (float*)alloc((size_t)E * 4);
    float* hA      = (float*)alloc((size_t)N * NODE * 4);    // h1, then h3 (in place)
    float* hB      = (float*)alloc((size_t)N * NODE * 4);    // h2, then h4 (in place)
    float* hvb     = (float*)alloc((size_t)N * NODE * 4);    // relu(V h) per depth
    float* colstat = (float*)alloc((size_t)2 * RD * 4);
    int*   gstart  = (int*)alloc((size_t)(G + 1) * 4);
    // medge (E*32 f32 = 102MB) and ybuf (N*256 f32 = 51MB): disjoint lifetimes.
    size_t big = (size_t)E * EDGEF * 4;
    size_t ybytes = (size_t)N * RD * 4;
    float* medge   = (float*)alloc(big > ybytes ? big : ybytes);
    float* ybuf    = medge;

    hipMemsetAsync(cnt, 0, (size_t)N * 4, stream);
    hipMemsetAsync(colstat, 0, (size_t)2 * RD * 4, stream);

    int eblocks = (E + 255) / 256;
    int sblocks = (N + 1023) / 1024;

    k_count<<<eblocks, 256, 0, stream>>>(dst, cnt, E);
    k_scanA<<<sblocks, 256, 0, stream>>>(cnt, starts, bsum, N);
    k_scanB<<<1, 64, 0, stream>>>(bsum, boff, sblocks, starts, N);
    k_scanC<<<(N + 255) / 256, 256, 0, stream>>>(boff, starts, cursor, N);
    k_fill_mij<<<eblocks, 256, 0, stream>>>(eattr, src, dst, wbonds, EW, Eb,
                                            cursor, esrc, ewS, medge, E);
    k_aggrE<<<1024, 256, 0, stream>>>(medge, starts, aggrE, N);

    int hvblocks = 512;
    int chunk = (N + hvblocks - 1) / hvblocks;

    // depth 0: h1 = mp(x)            (hA <- from x)
    k_hv<<<hvblocks, 256, 0, stream>>>(x, x, 0, VW, Vb, hvb, N, chunk);
    k_node<<<768, 512, 0, stream>>>(x, x, 0, hvb, starts, esrc, ewS, aggrE,
                                    UW, Ub, watoms, hA, N);
    // depth 1: h2 = mp(h1)           (hB <- from hA)
    k_hv<<<hvblocks, 256, 0, stream>>>(hA, hA, 0, VW, Vb, hvb, N, chunk);
    k_node<<<768, 512, 0, stream>>>(hA, hA, 0, hvb, starts, esrc, ewS, aggrE,
                                    UW, Ub, watoms, hB, N);
    // depth 2: h3 = mp(h1 + h2)      (hA <- in place, gather reads hvb only)
    k_hv<<<hvblocks, 256, 0, stream>>>(hA, hB, 1, VW, Vb, hvb, N, chunk);
    k_node<<<768, 512, 0, stream>>>(hA, hB, 1, hvb, starts, esrc, ewS, aggrE,
                                    UW, Ub, watoms, hA, N);
    // depth 3: h4 = mp(h2 + h3)      (hB <- in place)
    k_hv<<<hvblocks, 256, 0, stream>>>(hB, hA, 1, VW, Vb, hvb, N, chunk);
    k_node<<<768, 512, 0, stream>>>(hB, hA, 1, hvb, starts, esrc, ewS, aggrE,
                                    UW, Ub, watoms, hB, N);

    // readout: y = (h4 + x) @ R_W + R_b, BN stats fused
    k_y<<<512, 256, 0, stream>>>(hB, x, RW, Rb, ybuf, colstat, colstat + RD, N, chunk);
    k_gbounds<<<(N + 256) / 256, 256, 0, stream>>>(batch, gstart, N, G);
    k_out<<<G, RD, 0, stream>>>(ybuf, colstat, colstat + RD, Rg, Rbe, gstart, out, 1.0f / (float)N);
}

// Round 7
// 941.674 us; speedup vs baseline: 3.1138x; 1.3854x over previous
//
#include <hip/hip_runtime.h>
#include <cstdint>
#include <cstddef>

#define NODE 64
#define EDGEF 32
#define UPF 160   // 2*NODE + EDGEF
#define RD 256
#define UT_STRIDE 162  // 160 padded: float2 reads -> 2-way bank aliasing (free)

__device__ __forceinline__ float eluf(float x) { return x > 0.f ? x : expm1f(x); }

// ---------------------------------------------------------------------------
// CSR build
__global__ void k_count(const int* __restrict__ dst, int* cnt, int E) {
    int e = blockIdx.x * 256 + threadIdx.x;
    if (e < E) atomicAdd(&cnt[dst[e]], 1);
}

__global__ void k_scanA(const int* __restrict__ cnt, int* starts, int* bsum, int N) {
    __shared__ int sh[256];
    int t = threadIdx.x;
    int base = blockIdx.x * 1024 + t * 4;
    int v0 = 0, v1 = 0, v2 = 0, v3 = 0;
    if (base + 0 < N) v0 = cnt[base + 0];
    if (base + 1 < N) v1 = cnt[base + 1];
    if (base + 2 < N) v2 = cnt[base + 2];
    if (base + 3 < N) v3 = cnt[base + 3];
    int tot = v0 + v1 + v2 + v3;
    sh[t] = tot;
    __syncthreads();
    for (int off = 1; off < 256; off <<= 1) {
        int add = (t >= off) ? sh[t - off] : 0;
        __syncthreads();
        sh[t] += add;
        __syncthreads();
    }
    int excl = sh[t] - tot;
    if (base + 0 < N) starts[base + 0] = excl;
    if (base + 1 < N) starts[base + 1] = excl + v0;
    if (base + 2 < N) starts[base + 2] = excl + v0 + v1;
    if (base + 3 < N) starts[base + 3] = excl + v0 + v1 + v2;
    if (t == 255) bsum[blockIdx.x] = sh[255];
}

__global__ void k_scanB(const int* __restrict__ bsum, int* boff, int nb, int* starts, int N) {
    if (threadIdx.x == 0 && blockIdx.x == 0) {
        int run = 0;
        for (int b = 0; b < nb; ++b) { boff[b] = run; run += bsum[b]; }
        starts[N] = run;
    }
}

__global__ void k_scanC(const int* __restrict__ boff, int* starts, int* cursor, int N) {
    int i = blockIdx.x * 256 + threadIdx.x;
    if (i < N) {
        int v = starts[i] + boff[i >> 10];
        starts[i] = v;
        cursor[i] = v;
    }
}

// ---------------------------------------------------------------------------
// CSR fill: ids only (no 128B medge rows -- the edge FFN moved into k_aggrE).
__global__ void k_fill(const int* __restrict__ src, const int* __restrict__ dst,
                       const float* __restrict__ wb, int* cursor,
                       int* esrc, float* ewS, int* eidx, int E) {
    int e = blockIdx.x * 256 + threadIdx.x;
    if (e < E) {
        int pos = atomicAdd(&cursor[dst[e]], 1);
        esrc[pos] = src[e];
        ewS[pos] = wb[e];
        eidx[pos] = e;
    }
}

// ---------------------------------------------------------------------------
// Fused edge-FFN + segment sum: aggrE[n] = elu( sum_e w_e*relu(ea_e@E_W+E_b) ).
// Wave per node; half-wave (32 lanes = 32 channels) per edge, 2 edges/iter.
// E_W column in 32 VGPRs; gathered ea row broadcast via per-half-wave LDS slot.
__global__ __launch_bounds__(256, 6) void k_aggrE(
    const float* __restrict__ eattr, const int* __restrict__ eidx,
    const float* __restrict__ ewS, const int* __restrict__ starts,
    const float* __restrict__ EW, const float* __restrict__ Eb,
    float* __restrict__ aggrE_elu, int N) {
    __shared__ float slot[4][2][EDGEF];
    int tid = threadIdx.x;
    int lane = tid & 63, wid = tid >> 6;
    int half = lane >> 5, ch = lane & 31;
    float ewcol[EDGEF];
#pragma unroll
    for (int k = 0; k < EDGEF; ++k) ewcol[k] = EW[k * EDGEF + ch];
    float eb = Eb[ch];
    float* myslot = slot[wid][half];
    const float4* s4 = (const float4*)myslot;
    int nwaves = gridDim.x * 4;
    for (int n = blockIdx.x * 4 + wid; n < N; n += nwaves) {
        int s0 = starts[n], s1 = starts[n + 1];
        float acc = 0.f;
        int i = s0 + half;
        float aC = 0.f;
        if (i < s1) aC = eattr[(size_t)eidx[i] * EDGEF + ch];
        for (; i < s1; i += 2) {
            float aN = 0.f;
            if (i + 2 < s1) aN = eattr[(size_t)eidx[i + 2] * EDGEF + ch];
            myslot[ch] = aC;
            float m0 = eb, m1 = 0.f;
#pragma unroll
            for (int q = 0; q < 8; ++q) {
                float4 a4 = s4[q];
                m0 = fmaf(a4.x, ewcol[4*q+0], m0);
                m1 = fmaf(a4.y, ewcol[4*q+1], m1);
                m0 = fmaf(a4.z, ewcol[4*q+2], m0);
                m1 = fmaf(a4.w, ewcol[4*q+3], m1);
            }
            acc = fmaf(ewS[i], fmaxf(m0 + m1, 0.f), acc);
            aC = aN;
        }
        acc += __shfl_xor(acc, 32, 64);
        if (lane < EDGEF) aggrE_elu[(size_t)n * EDGEF + lane] = eluf(acc);
    }
}

// ---------------------------------------------------------------------------
// hv = relu((ha [+ hb]) @ V_W + V_b)  -- dense per-node transform, once per
// depth, so the edge loop is a pure gather of precomputed rows.
__global__ __launch_bounds__(256) void k_hv(
    const float* __restrict__ ha, const float* __restrict__ hb, int addB,
    const float* __restrict__ VW, const float* __restrict__ Vb,
    float* __restrict__ hv, int N, int chunk) {
    __shared__ float slot[4][NODE];
    int tid = threadIdx.x;
    int lane = tid & 63, w = tid >> 6;
    float vcol[NODE];
#pragma unroll
    for (int k = 0; k < NODE; ++k) vcol[k] = VW[k * NODE + lane];
    float vb = Vb[lane];
    const float4* s4 = (const float4*)slot[w];
    int n0 = blockIdx.x * chunk;
    int n1 = n0 + chunk; if (n1 > N) n1 = N;
    for (int n = n0 + w; n < n1; n += 4) {
        float hrow = ha[(size_t)n * NODE + lane];
        if (addB) hrow += hb[(size_t)n * NODE + lane];
        slot[w][lane] = hrow;
        float d0 = 0.f, d1 = 0.f, d2 = 0.f, d3 = 0.f;
#pragma unroll
        for (int q = 0; q < 16; ++q) {
            float4 h4 = s4[q];
            d0 = fmaf(h4.x, vcol[4*q+0], d0);
            d1 = fmaf(h4.y, vcol[4*q+1], d1);
            d2 = fmaf(h4.z, vcol[4*q+2], d2);
            d3 = fmaf(h4.w, vcol[4*q+3], d3);
        }
        hv[(size_t)n * NODE + lane] = fmaxf(vb + ((d0 + d1) + (d2 + d3)), 0.f);
    }
}

// ---------------------------------------------------------------------------
// Pure gather: aggr[n] = sum_e w_e * hv[src_e]. No LDS, ~30 VGPRs -> 8
// waves/SIMD; 4-deep row prefetch for memory-level parallelism.
__global__ __launch_bounds__(512, 8) void k_gather(
    const float* __restrict__ hv, const int* __restrict__ starts,
    const int* __restrict__ esrc, const float* __restrict__ ewS,
    float* __restrict__ aggr, int N) {
    int lane = threadIdx.x & 63, wid = threadIdx.x >> 6;
    int nwaves = gridDim.x * 8;
    for (int n = blockIdx.x * 8 + wid; n < N; n += nwaves) {
        int s0 = starts[n], s1 = starts[n + 1];
        int deg = s1 - s0;
        float acc = 0.f;
        float r0 = 0.f, r1 = 0.f, r2 = 0.f, r3 = 0.f;
        if (deg > 0) r0 = hv[(size_t)esrc[s0 + 0] * NODE + lane];
        if (deg > 1) r1 = hv[(size_t)esrc[s0 + 1] * NODE + lane];
        if (deg > 2) r2 = hv[(size_t)esrc[s0 + 2] * NODE + lane];
        if (deg > 3) r3 = hv[(size_t)esrc[s0 + 3] * NODE + lane];
        for (int i = 0; i < deg; ++i) {
            float rN = 0.f;
            if (i + 4 < deg) rN = hv[(size_t)esrc[s0 + i + 4] * NODE + lane];
            acc = fmaf(ewS[s0 + i], r0, acc);
            r0 = r1; r1 = r2; r2 = r3; r3 = rN;
        }
        aggr[(size_t)n * NODE + lane] = acc;
    }
}

// ---------------------------------------------------------------------------
// Dense node update: up = elu([aggr | aggrE | h_n]) -> U-FFN -> h_out.
// Streaming reads; LDS holds U^T tile. In-place h_out aliasing ha is safe
// (each thread reads/writes only its own element).
__global__ __launch_bounds__(512, 4) void k_update(
    const float* __restrict__ ha, const float* __restrict__ hb, int addB,
    const float* __restrict__ aggr, const float* __restrict__ aggrE_elu,
    const float* __restrict__ UW, const float* __restrict__ Ub,
    const float* __restrict__ watoms, float* __restrict__ h_out, int N) {
    __shared__ float lds_Ut[NODE * UT_STRIDE];   // 41.4 KB
    __shared__ float lds_up[8 * UPF];            // 5 KB
    int tid = threadIdx.x;
    for (int idx = tid; idx < UPF * NODE; idx += 512) {
        int j = idx & 63, t2 = idx >> 6;
        lds_Ut[j * UT_STRIDE + t2] = UW[idx];
    }
    int lane = tid & 63, wid = tid >> 6;
    float ub = Ub[lane];
    __syncthreads();
    float* myup = lds_up + wid * UPF;
    int nwaves = gridDim.x * 8;
    for (int n = blockIdx.x * 8 + wid; n < N; n += nwaves) {
        myup[lane] = eluf(aggr[(size_t)n * NODE + lane]);
        if (lane < EDGEF) myup[NODE + lane] = aggrE_elu[(size_t)n * EDGEF + lane];
        float hrow = ha[(size_t)n * NODE + lane];
        if (addB) hrow += hb[(size_t)n * NODE + lane];
        myup[NODE + EDGEF + lane] = eluf(hrow);
        float o = ub;
#pragma unroll
        for (int t2 = 0; t2 < UPF; t2 += 2) {
            float2 u2 = *(const float2*)&myup[t2];                 // broadcast
            float2 w2 = *(const float2*)&lds_Ut[lane * UT_STRIDE + t2];
            o = fmaf(u2.x, w2.x, o);
            o = fmaf(u2.y, w2.y, o);
        }
        h_out[(size_t)n * NODE + lane] = fmaxf(o, 0.f) * watoms[n];
    }
}

// ---------------------------------------------------------------------------
// Readout GEMM y = (ha+hb) @ R_W + R_b, fused BN column stats.
__global__ __launch_bounds__(256) void k_y(
    const float* __restrict__ ha, const float* __restrict__ hb,
    const float* __restrict__ RW, const float* __restrict__ Rb,
    float* __restrict__ y, float* colsum, float* colsumsq, int N, int chunk) {
    __shared__ float slot[4][NODE];
    int tid = threadIdx.x;
    int lane = tid & 63, w = tid >> 6;
    float rcol[NODE];
#pragma unroll
    for (int k = 0; k < NODE; ++k) rcol[k] = RW[k * RD + w * 64 + lane];
    float rb = Rb[w * 64 + lane];
    const float4* s4 = (const float4*)slot[w];
    float sum = 0.f, sq = 0.f;
    int n0 = blockIdx.x * chunk;
    int n1 = n0 + chunk; if (n1 > N) n1 = N;
    for (int n = n0; n < n1; ++n) {
        float hvC = ha[(size_t)n * NODE + lane] + hb[(size_t)n * NODE + lane];
        slot[w][lane] = hvC;
        float d0 = 0.f, d1 = 0.f, d2 = 0.f, d3 = 0.f;
#pragma unroll
        for (int q = 0; q < 16; ++q) {
            float4 h4 = s4[q];
            d0 = fmaf(h4.x, rcol[4*q+0], d0);
            d1 = fmaf(h4.y, rcol[4*q+1], d1);
            d2 = fmaf(h4.z, rcol[4*q+2], d2);
            d3 = fmaf(h4.w, rcol[4*q+3], d3);
        }
        float v = rb + ((d0 + d1) + (d2 + d3));
        y[(size_t)n * RD + w * 64 + lane] = v;
        sum += v; sq = fmaf(v, v, sq);
    }
    atomicAdd(&colsum[w * 64 + lane], sum);
    atomicAdd(&colsumsq[w * 64 + lane], sq);
}

// graph boundaries from sorted batch: gstart[g] = first n with batch[n] >= g
__global__ void k_gbounds(const int* __restrict__ batch, int* gstart, int N, int G) {
    int n = blockIdx.x * 256 + threadIdx.x;
    if (n > N) return;
    int bprev = (n == 0) ? -1 : batch[n - 1];
    int bcur = (n == N) ? G : batch[n];
    for (int g = bprev + 1; g <= bcur; ++g) gstart[g] = n;
}

// BN(normalize) + relu + segment mean. block per graph, thread per channel.
__global__ void k_out(const float* __restrict__ y, const float* __restrict__ colsum,
                      const float* __restrict__ colsumsq, const float* __restrict__ gamma,
                      const float* __restrict__ beta, const int* __restrict__ gstart,
                      float* __restrict__ out, float invN) {
    int g = blockIdx.x, c = threadIdx.x;
    float mu = colsum[c] * invN;
    float var = fmaxf(colsumsq[c] * invN - mu * mu, 0.f);
    float inv = rsqrtf(var + 1e-5f);
    float ga = gamma[c], be = beta[c];
    int a = gstart[g], b = gstart[g + 1];
    float acc = 0.f;
    for (int n = a; n < b; ++n) {
        float v = y[(size_t)n * RD + c];
        acc += fmaxf(fmaf((v - mu) * inv, ga, be), 0.f);
    }
    out[(size_t)g * RD + c] = acc / fmaxf((float)(b - a), 1.f);
}

// ---------------------------------------------------------------------------
extern "C" void kernel_launch(void* const* d_in, const int* in_sizes, int n_in,
                              void* d_out, int out_size, void* d_ws, size_t ws_size,
                              hipStream_t stream) {
    const float* x      = (const float*)d_in[0];
    const int*   ei     = (const int*)d_in[1];
    const float* eattr  = (const float*)d_in[2];
    const float* watoms = (const float*)d_in[3];
    const float* wbonds = (const float*)d_in[4];
    const int*   batch  = (const int*)d_in[5];
    const float* VW = (const float*)d_in[6];
    const float* Vb = (const float*)d_in[7];
    const float* EW = (const float*)d_in[8];
    const float* Eb = (const float*)d_in[9];
    const float* UW = (const float*)d_in[10];
    const float* Ub = (const float*)d_in[11];
    const float* RW = (const float*)d_in[12];
    const float* Rb = (const float*)d_in[13];
    const float* Rg = (const float*)d_in[14];
    const float* Rbe = (const float*)d_in[15];
    float* out = (float*)d_out;

    const int N = in_sizes[0] / NODE;
    const int E = in_sizes[4];
    const int G = out_size / RD;
    const int* src = ei;
    const int* dst = ei + E;

    char* p = (char*)d_ws;
    auto alloc = [&](size_t bytes) -> char* {
        char* r = p;
        p += (bytes + 255) & ~(size_t)255;
        return r;
    };
    float* aggrE   = (float*)alloc((size_t)N * EDGEF * 4);   // stores elu(aggrE)
    int*   cnt     = (int*)alloc((size_t)N * 4);
    int*   starts  = (int*)alloc((size_t)(N + 1) * 4);
    int*   cursor  = (int*)alloc((size_t)N * 4);
    int*   bsum    = (int*)alloc(64 * 4);
    int*   boff    = (int*)alloc(64 * 4);
    int*   esrc    = (int*)alloc((size_t)E * 4);
    float* ewS     = (float*)alloc((size_t)E * 4);
    int*   eidx    = (int*)alloc((size_t)E * 4);
    float* hA      = (float*)alloc((size_t)N * NODE * 4);    // h1, then h3 (in place)
    float* hB      = (float*)alloc((size_t)N * NODE * 4);    // h2, then h4 (in place)
    float* hvb     = (float*)alloc((size_t)N * NODE * 4);    // relu(V h) per depth
    float* aggr    = (float*)alloc((size_t)N * NODE * 4);    // gathered node messages
    float* colstat = (float*)alloc((size_t)2 * RD * 4);
    int*   gstart  = (int*)alloc((size_t)(G + 1) * 4);
    float* ybuf    = (float*)alloc((size_t)N * RD * 4);

    hipMemsetAsync(cnt, 0, (size_t)N * 4, stream);
    hipMemsetAsync(colstat, 0, (size_t)2 * RD * 4, stream);

    int eblocks = (E + 255) / 256;
    int sblocks = (N + 1023) / 1024;

    k_count<<<eblocks, 256, 0, stream>>>(dst, cnt, E);
    k_scanA<<<sblocks, 256, 0, stream>>>(cnt, starts, bsum, N);
    k_scanB<<<1, 64, 0, stream>>>(bsum, boff, sblocks, starts, N);
    k_scanC<<<(N + 255) / 256, 256, 0, stream>>>(boff, starts, cursor, N);
    k_fill<<<eblocks, 256, 0, stream>>>(src, dst, wbonds, cursor, esrc, ewS, eidx, E);
    k_aggrE<<<2048, 256, 0, stream>>>(eattr, eidx, ewS, starts, EW, Eb, aggrE, N);

    int hvblocks = 512;
    int chunk = (N + hvblocks - 1) / hvblocks;

    // depth 0: h1 = mp(x)
    k_hv<<<hvblocks, 256, 0, stream>>>(x, x, 0, VW, Vb, hvb, N, chunk);
    k_gather<<<2048, 512, 0, stream>>>(hvb, starts, esrc, ewS, aggr, N);
    k_update<<<768, 512, 0, stream>>>(x, x, 0, aggr, aggrE, UW, Ub, watoms, hA, N);
    // depth 1: h2 = mp(h1)
    k_hv<<<hvblocks, 256, 0, stream>>>(hA, hA, 0, VW, Vb, hvb, N, chunk);
    k_gather<<<2048, 512, 0, stream>>>(hvb, starts, esrc, ewS, aggr, N);
    k_update<<<768, 512, 0, stream>>>(hA, hA, 0, aggr, aggrE, UW, Ub, watoms, hB, N);
    // depth 2: h3 = mp(h1 + h2)   (in place into hA)
    k_hv<<<hvblocks, 256, 0, stream>>>(hA, hB, 1, VW, Vb, hvb, N, chunk);
    k_gather<<<2048, 512, 0, stream>>>(hvb, starts, esrc, ewS, aggr, N);
    k_update<<<768, 512, 0, stream>>>(hA, hB, 1, aggr, aggrE, UW, Ub, watoms, hA, N);
    // depth 3: h4 = mp(h2 + h3)   (in place into hB)
    k_hv<<<hvblocks, 256, 0, stream>>>(hB, hA, 1, VW, Vb, hvb, N, chunk);
    k_gather<<<2048, 512, 0, stream>>>(hvb, starts, esrc, ewS, aggr, N);
    k_update<<<768, 512, 0, stream>>>(hB, hA, 1, aggr, aggrE, UW, Ub, watoms, hB, N);

    // readout: y = (h4 + x) @ R_W + R_b, BN stats fused
    k_y<<<512, 256, 0, stream>>>(hB, x, RW, Rb, ybuf, colstat, colstat + RD, N, chunk);
    k_gbounds<<<(N + 256) / 256, 256, 0, stream>>>(batch, gstart, N, G);
    k_out<<<G, RD, 0, stream>>>(ybuf, colstat, colstat + RD, Rg, Rbe, gstart, out, 1.0f / (float)N);
}

// Round 8
// 675.782 us; speedup vs baseline: 4.3389x; 1.3935x over previous
//
#include <hip/hip_runtime.h>
#include <cstdint>
#include <cstddef>

#define NODE 64
#define EDGEF 32
#define UPF 160   // 2*NODE + EDGEF
#define RD 256
#define UT_STRIDE 162  // 160 padded: float2 reads -> 2-way bank aliasing (free)

__device__ __forceinline__ float eluf(float x) { return x > 0.f ? x : expm1f(x); }

// ---------------------------------------------------------------------------
// CSR build
__global__ void k_count(const int* __restrict__ dst, int* cnt, int E) {
    int e = blockIdx.x * 256 + threadIdx.x;
    if (e < E) atomicAdd(&cnt[dst[e]], 1);
}

__global__ void k_scanA(const int* __restrict__ cnt, int* starts, int* bsum, int N) {
    __shared__ int sh[256];
    int t = threadIdx.x;
    int base = blockIdx.x * 1024 + t * 4;
    int v0 = 0, v1 = 0, v2 = 0, v3 = 0;
    if (base + 0 < N) v0 = cnt[base + 0];
    if (base + 1 < N) v1 = cnt[base + 1];
    if (base + 2 < N) v2 = cnt[base + 2];
    if (base + 3 < N) v3 = cnt[base + 3];
    int tot = v0 + v1 + v2 + v3;
    sh[t] = tot;
    __syncthreads();
    for (int off = 1; off < 256; off <<= 1) {
        int add = (t >= off) ? sh[t - off] : 0;
        __syncthreads();
        sh[t] += add;
        __syncthreads();
    }
    int excl = sh[t] - tot;
    if (base + 0 < N) starts[base + 0] = excl;
    if (base + 1 < N) starts[base + 1] = excl + v0;
    if (base + 2 < N) starts[base + 2] = excl + v0 + v1;
    if (base + 3 < N) starts[base + 3] = excl + v0 + v1 + v2;
    if (t == 255) bsum[blockIdx.x] = sh[255];
}

__global__ void k_scanB(const int* __restrict__ bsum, int* boff, int nb, int* starts, int N) {
    if (threadIdx.x == 0 && blockIdx.x == 0) {
        int run = 0;
        for (int b = 0; b < nb; ++b) { boff[b] = run; run += bsum[b]; }
        starts[N] = run;
    }
}

__global__ void k_scanC(const int* __restrict__ boff, int* starts, int* cursor, int N) {
    int i = blockIdx.x * 256 + threadIdx.x;
    if (i < N) {
        int v = starts[i] + boff[i >> 10];
        starts[i] = v;
        cursor[i] = v;
    }
}

// ---------------------------------------------------------------------------
// CSR fill: ids only (no 128B medge rows -- the edge FFN moved into k_aggrE).
__global__ void k_fill(const int* __restrict__ src, const int* __restrict__ dst,
                       const float* __restrict__ wb, int* cursor,
                       int* esrc, float* ewS, int* eidx, int E) {
    int e = blockIdx.x * 256 + threadIdx.x;
    if (e < E) {
        int pos = atomicAdd(&cursor[dst[e]], 1);
        esrc[pos] = src[e];
        ewS[pos] = wb[e];
        eidx[pos] = e;
    }
}

// ---------------------------------------------------------------------------
// Fused edge-FFN + segment sum: aggrE[n] = elu( sum_e w_e*relu(ea_e@E_W+E_b) ).
// Wave per node; half-wave (32 lanes = 32 channels) per edge, 2 edges/iter.
__global__ __launch_bounds__(256, 6) void k_aggrE(
    const float* __restrict__ eattr, const int* __restrict__ eidx,
    const float* __restrict__ ewS, const int* __restrict__ starts,
    const float* __restrict__ EW, const float* __restrict__ Eb,
    float* __restrict__ aggrE_elu, int N) {
    __shared__ float slot[4][2][EDGEF];
    int tid = threadIdx.x;
    int lane = tid & 63, wid = tid >> 6;
    int half = lane >> 5, ch = lane & 31;
    float ewcol[EDGEF];
#pragma unroll
    for (int k = 0; k < EDGEF; ++k) ewcol[k] = EW[k * EDGEF + ch];
    float eb = Eb[ch];
    float* myslot = slot[wid][half];
    const float4* s4 = (const float4*)myslot;
    int nwaves = gridDim.x * 4;
    for (int n = blockIdx.x * 4 + wid; n < N; n += nwaves) {
        int s0 = starts[n], s1 = starts[n + 1];
        float acc = 0.f;
        int i = s0 + half;
        float aC = 0.f;
        if (i < s1) aC = eattr[(size_t)eidx[i] * EDGEF + ch];
        for (; i < s1; i += 2) {
            float aN = 0.f;
            if (i + 2 < s1) aN = eattr[(size_t)eidx[i + 2] * EDGEF + ch];
            myslot[ch] = aC;
            float m0 = eb, m1 = 0.f;
#pragma unroll
            for (int q = 0; q < 8; ++q) {
                float4 a4 = s4[q];
                m0 = fmaf(a4.x, ewcol[4*q+0], m0);
                m1 = fmaf(a4.y, ewcol[4*q+1], m1);
                m0 = fmaf(a4.z, ewcol[4*q+2], m0);
                m1 = fmaf(a4.w, ewcol[4*q+3], m1);
            }
            acc = fmaf(ewS[i], fmaxf(m0 + m1, 0.f), acc);
            aC = aN;
        }
        acc += __shfl_xor(acc, 32, 64);
        if (lane < EDGEF) aggrE_elu[(size_t)n * EDGEF + lane] = eluf(acc);
    }
}

// ---------------------------------------------------------------------------
// hv = relu((ha [+ hb]) @ V_W + V_b)  -- dense per-node transform, once per
// depth, so the edge loop is a pure gather of precomputed rows.
__global__ __launch_bounds__(256) void k_hv(
    const float* __restrict__ ha, const float* __restrict__ hb, int addB,
    const float* __restrict__ VW, const float* __restrict__ Vb,
    float* __restrict__ hv, int N, int chunk) {
    __shared__ float slot[4][NODE];
    int tid = threadIdx.x;
    int lane = tid & 63, w = tid >> 6;
    float vcol[NODE];
#pragma unroll
    for (int k = 0; k < NODE; ++k) vcol[k] = VW[k * NODE + lane];
    float vb = Vb[lane];
    const float4* s4 = (const float4*)slot[w];
    int n0 = blockIdx.x * chunk;
    int n1 = n0 + chunk; if (n1 > N) n1 = N;
    for (int n = n0 + w; n < n1; n += 4) {
        float hrow = ha[(size_t)n * NODE + lane];
        if (addB) hrow += hb[(size_t)n * NODE + lane];
        slot[w][lane] = hrow;
        float d0 = 0.f, d1 = 0.f, d2 = 0.f, d3 = 0.f;
#pragma unroll
        for (int q = 0; q < 16; ++q) {
            float4 h4 = s4[q];
            d0 = fmaf(h4.x, vcol[4*q+0], d0);
            d1 = fmaf(h4.y, vcol[4*q+1], d1);
            d2 = fmaf(h4.z, vcol[4*q+2], d2);
            d3 = fmaf(h4.w, vcol[4*q+3], d3);
        }
        hv[(size_t)n * NODE + lane] = fmaxf(vb + ((d0 + d1) + (d2 + d3)), 0.f);
    }
}

// ---------------------------------------------------------------------------
// Pure gather: aggr[n] = sum_e w_e * hv[src_e]. Quarter-wave edge parallelism:
// each 16-lane group loads a different edge's row as float4 (256B/instr),
// 4 edges concurrent x 2-deep prefetch = 8 rows in flight per wave, deg/4
// loop iterations. Cross-group combine: 8 shfl_xor at the end.
__global__ __launch_bounds__(512, 8) void k_gather(
    const float* __restrict__ hv, const int* __restrict__ starts,
    const int* __restrict__ esrc, const float* __restrict__ ewS,
    float* __restrict__ aggr, int N) {
    int lane = threadIdx.x & 63, wid = threadIdx.x >> 6;
    int grp = lane >> 4, gl = lane & 15;
    int nwaves = gridDim.x * 8;
    for (int n = blockIdx.x * 8 + wid; n < N; n += nwaves) {
        int s0 = starts[n], s1 = starts[n + 1];
        int deg = s1 - s0;
        float4 acc = {0.f, 0.f, 0.f, 0.f};
        float4 r0 = {0.f, 0.f, 0.f, 0.f}, r1 = {0.f, 0.f, 0.f, 0.f};
        float w0 = 0.f, w1 = 0.f;
        if (grp < deg) {
            r0 = *(const float4*)(hv + (size_t)esrc[s0 + grp] * NODE + gl * 4);
            w0 = ewS[s0 + grp];
        }
        if (grp + 4 < deg) {
            r1 = *(const float4*)(hv + (size_t)esrc[s0 + grp + 4] * NODE + gl * 4);
            w1 = ewS[s0 + grp + 4];
        }
        for (int i = grp; i < deg; i += 4) {
            float4 rN = {0.f, 0.f, 0.f, 0.f};
            float wN = 0.f;
            if (i + 8 < deg) {
                rN = *(const float4*)(hv + (size_t)esrc[s0 + i + 8] * NODE + gl * 4);
                wN = ewS[s0 + i + 8];
            }
            acc.x = fmaf(w0, r0.x, acc.x);
            acc.y = fmaf(w0, r0.y, acc.y);
            acc.z = fmaf(w0, r0.z, acc.z);
            acc.w = fmaf(w0, r0.w, acc.w);
            r0 = r1; w0 = w1;
            r1 = rN; w1 = wN;
        }
        // combine the 4 groups: channels live at lanes gl, gl+16, gl+32, gl+48
        acc.x += __shfl_xor(acc.x, 16, 64);
        acc.y += __shfl_xor(acc.y, 16, 64);
        acc.z += __shfl_xor(acc.z, 16, 64);
        acc.w += __shfl_xor(acc.w, 16, 64);
        acc.x += __shfl_xor(acc.x, 32, 64);
        acc.y += __shfl_xor(acc.y, 32, 64);
        acc.z += __shfl_xor(acc.z, 32, 64);
        acc.w += __shfl_xor(acc.w, 32, 64);
        if (lane < 16)
            *(float4*)(aggr + (size_t)n * NODE + gl * 4) = acc;
    }
}

// ---------------------------------------------------------------------------
// Dense node update: up = elu([aggr | aggrE | h_n]) -> U-FFN -> h_out.
__global__ __launch_bounds__(512, 4) void k_update(
    const float* __restrict__ ha, const float* __restrict__ hb, int addB,
    const float* __restrict__ aggr, const float* __restrict__ aggrE_elu,
    const float* __restrict__ UW, const float* __restrict__ Ub,
    const float* __restrict__ watoms, float* __restrict__ h_out, int N) {
    __shared__ float lds_Ut[NODE * UT_STRIDE];   // 41.4 KB
    __shared__ float lds_up[8 * UPF];            // 5 KB
    int tid = threadIdx.x;
    for (int idx = tid; idx < UPF * NODE; idx += 512) {
        int j = idx & 63, t2 = idx >> 6;
        lds_Ut[j * UT_STRIDE + t2] = UW[idx];
    }
    int lane = tid & 63, wid = tid >> 6;
    float ub = Ub[lane];
    __syncthreads();
    float* myup = lds_up + wid * UPF;
    int nwaves = gridDim.x * 8;
    for (int n = blockIdx.x * 8 + wid; n < N; n += nwaves) {
        myup[lane] = eluf(aggr[(size_t)n * NODE + lane]);
        if (lane < EDGEF) myup[NODE + lane] = aggrE_elu[(size_t)n * EDGEF + lane];
        float hrow = ha[(size_t)n * NODE + lane];
        if (addB) hrow += hb[(size_t)n * NODE + lane];
        myup[NODE + EDGEF + lane] = eluf(hrow);
        float o = ub;
#pragma unroll
        for (int t2 = 0; t2 < UPF; t2 += 2) {
            float2 u2 = *(const float2*)&myup[t2];                 // broadcast
            float2 w2 = *(const float2*)&lds_Ut[lane * UT_STRIDE + t2];
            o = fmaf(u2.x, w2.x, o);
            o = fmaf(u2.y, w2.y, o);
        }
        h_out[(size_t)n * NODE + lane] = fmaxf(o, 0.f) * watoms[n];
    }
}

// ---------------------------------------------------------------------------
// Readout GEMM y = (ha+hb) @ R_W + R_b, fused BN column stats.
__global__ __launch_bounds__(256) void k_y(
    const float* __restrict__ ha, const float* __restrict__ hb,
    const float* __restrict__ RW, const float* __restrict__ Rb,
    float* __restrict__ y, float* colsum, float* colsumsq, int N, int chunk) {
    __shared__ float slot[4][NODE];
    int tid = threadIdx.x;
    int lane = tid & 63, w = tid >> 6;
    float rcol[NODE];
#pragma unroll
    for (int k = 0; k < NODE; ++k) rcol[k] = RW[k * RD + w * 64 + lane];
    float rb = Rb[w * 64 + lane];
    const float4* s4 = (const float4*)slot[w];
    float sum = 0.f, sq = 0.f;
    int n0 = blockIdx.x * chunk;
    int n1 = n0 + chunk; if (n1 > N) n1 = N;
    for (int n = n0; n < n1; ++n) {
        float hvC = ha[(size_t)n * NODE + lane] + hb[(size_t)n * NODE + lane];
        slot[w][lane] = hvC;
        float d0 = 0.f, d1 = 0.f, d2 = 0.f, d3 = 0.f;
#pragma unroll
        for (int q = 0; q < 16; ++q) {
            float4 h4 = s4[q];
            d0 = fmaf(h4.x, rcol[4*q+0], d0);
            d1 = fmaf(h4.y, rcol[4*q+1], d1);
            d2 = fmaf(h4.z, rcol[4*q+2], d2);
            d3 = fmaf(h4.w, rcol[4*q+3], d3);
        }
        float v = rb + ((d0 + d1) + (d2 + d3));
        y[(size_t)n * RD + w * 64 + lane] = v;
        sum += v; sq = fmaf(v, v, sq);
    }
    atomicAdd(&colsum[w * 64 + lane], sum);
    atomicAdd(&colsumsq[w * 64 + lane], sq);
}

// graph boundaries from sorted batch: gstart[g] = first n with batch[n] >= g
__global__ void k_gbounds(const int* __restrict__ batch, int* gstart, int N, int G) {
    int n = blockIdx.x * 256 + threadIdx.x;
    if (n > N) return;
    int bprev = (n == 0) ? -1 : batch[n - 1];
    int bcur = (n == N) ? G : batch[n];
    for (int g = bprev + 1; g <= bcur; ++g) gstart[g] = n;
}

// BN(normalize) + relu + segment mean. block per graph, thread per channel.
__global__ void k_out(const float* __restrict__ y, const float* __restrict__ colsum,
                      const float* __restrict__ colsumsq, const float* __restrict__ gamma,
                      const float* __restrict__ beta, const int* __restrict__ gstart,
                      float* __restrict__ out, float invN) {
    int g = blockIdx.x, c = threadIdx.x;
    float mu = colsum[c] * invN;
    float var = fmaxf(colsumsq[c] * invN - mu * mu, 0.f);
    float inv = rsqrtf(var + 1e-5f);
    float ga = gamma[c], be = beta[c];
    int a = gstart[g], b = gstart[g + 1];
    float acc = 0.f;
    for (int n = a; n < b; ++n) {
        float v = y[(size_t)n * RD + c];
        acc += fmaxf(fmaf((v - mu) * inv, ga, be), 0.f);
    }
    out[(size_t)g * RD + c] = acc / fmaxf((float)(b - a), 1.f);
}

// ---------------------------------------------------------------------------
extern "C" void kernel_launch(void* const* d_in, const int* in_sizes, int n_in,
                              void* d_out, int out_size, void* d_ws, size_t ws_size,
                              hipStream_t stream) {
    const float* x      = (const float*)d_in[0];
    const int*   ei     = (const int*)d_in[1];
    const float* eattr  = (const float*)d_in[2];
    const float* watoms = (const float*)d_in[3];
    const float* wbonds = (const float*)d_in[4];
    const int*   batch  = (const int*)d_in[5];
    const float* VW = (const float*)d_in[6];
    const float* Vb = (const float*)d_in[7];
    const float* EW = (const float*)d_in[8];
    const float* Eb = (const float*)d_in[9];
    const float* UW = (const float*)d_in[10];
    const float* Ub = (const float*)d_in[11];
    const float* RW = (const float*)d_in[12];
    const float* Rb = (const float*)d_in[13];
    const float* Rg = (const float*)d_in[14];
    const float* Rbe = (const float*)d_in[15];
    float* out = (float*)d_out;

    const int N = in_sizes[0] / NODE;
    const int E = in_sizes[4];
    const int G = out_size / RD;
    const int* src = ei;
    const int* dst = ei + E;

    char* p = (char*)d_ws;
    auto alloc = [&](size_t bytes) -> char* {
        char* r = p;
        p += (bytes + 255) & ~(size_t)255;
        return r;
    };
    float* aggrE   = (float*)alloc((size_t)N * EDGEF * 4);   // stores elu(aggrE)
    int*   cnt     = (int*)alloc((size_t)N * 4);
    int*   starts  = (int*)alloc((size_t)(N + 1) * 4);
    int*   cursor  = (int*)alloc((size_t)N * 4);
    int*   bsum    = (int*)alloc(64 * 4);
    int*   boff    = (int*)alloc(64 * 4);
    int*   esrc    = (int*)alloc((size_t)E * 4);
    float* ewS     = (float*)alloc((size_t)E * 4);
    int*   eidx    = (int*)alloc((size_t)E * 4);
    float* hA      = (float*)alloc((size_t)N * NODE * 4);    // h1, then h3 (in place)
    float* hB      = (float*)alloc((size_t)N * NODE * 4);    // h2, then h4 (in place)
    float* hvb     = (float*)alloc((size_t)N * NODE * 4);    // relu(V h) per depth
    float* aggr    = (float*)alloc((size_t)N * NODE * 4);    // gathered node messages
    float* colstat = (float*)alloc((size_t)2 * RD * 4);
    int*   gstart  = (int*)alloc((size_t)(G + 1) * 4);
    float* ybuf    = (float*)alloc((size_t)N * RD * 4);

    hipMemsetAsync(cnt, 0, (size_t)N * 4, stream);
    hipMemsetAsync(colstat, 0, (size_t)2 * RD * 4, stream);

    int eblocks = (E + 255) / 256;
    int sblocks = (N + 1023) / 1024;

    k_count<<<eblocks, 256, 0, stream>>>(dst, cnt, E);
    k_scanA<<<sblocks, 256, 0, stream>>>(cnt, starts, bsum, N);
    k_scanB<<<1, 64, 0, stream>>>(bsum, boff, sblocks, starts, N);
    k_scanC<<<(N + 255) / 256, 256, 0, stream>>>(boff, starts, cursor, N);
    k_fill<<<eblocks, 256, 0, stream>>>(src, dst, wbonds, cursor, esrc, ewS, eidx, E);
    k_aggrE<<<2048, 256, 0, stream>>>(eattr, eidx, ewS, starts, EW, Eb, aggrE, N);

    int hvblocks = 512;
    int chunk = (N + hvblocks - 1) / hvblocks;

    // depth 0: h1 = mp(x)
    k_hv<<<hvblocks, 256, 0, stream>>>(x, x, 0, VW, Vb, hvb, N, chunk);
    k_gather<<<2048, 512, 0, stream>>>(hvb, starts, esrc, ewS, aggr, N);
    k_update<<<768, 512, 0, stream>>>(x, x, 0, aggr, aggrE, UW, Ub, watoms, hA, N);
    // depth 1: h2 = mp(h1)
    k_hv<<<hvblocks, 256, 0, stream>>>(hA, hA, 0, VW, Vb, hvb, N, chunk);
    k_gather<<<2048, 512, 0, stream>>>(hvb, starts, esrc, ewS, aggr, N);
    k_update<<<768, 512, 0, stream>>>(hA, hA, 0, aggr, aggrE, UW, Ub, watoms, hB, N);
    // depth 2: h3 = mp(h1 + h2)   (in place into hA)
    k_hv<<<hvblocks, 256, 0, stream>>>(hA, hB, 1, VW, Vb, hvb, N, chunk);
    k_gather<<<2048, 512, 0, stream>>>(hvb, starts, esrc, ewS, aggr, N);
    k_update<<<768, 512, 0, stream>>>(hA, hB, 1, aggr, aggrE, UW, Ub, watoms, hA, N);
    // depth 3: h4 = mp(h2 + h3)   (in place into hB)
    k_hv<<<hvblocks, 256, 0, stream>>>(hB, hA, 1, VW, Vb, hvb, N, chunk);
    k_gather<<<2048, 512, 0, stream>>>(hvb, starts, esrc, ewS, aggr, N);
    k_update<<<768, 512, 0, stream>>>(hB, hA, 1, aggr, aggrE, UW, Ub, watoms, hB, N);

    // readout: y = (h4 + x) @ R_W + R_b, BN stats fused
    k_y<<<512, 256, 0, stream>>>(hB, x, RW, Rb, ybuf, colstat, colstat + RD, N, chunk);
    k_gbounds<<<(N + 256) / 256, 256, 0, stream>>>(batch, gstart, N, G);
    k_out<<<G, RD, 0, stream>>>(ybuf, colstat, colstat + RD, Rg, Rbe, gstart, out, 1.0f / (float)N);
}